// Round 6
// baseline (244.979 us; speedup 1.0000x reference)
//
#include <hip/hip_runtime.h>
#include <hip/hip_bf16.h>

// GraphSAGE 2-layer, N=100K, E=1.6M, 128->128(relu)->64, log_softmax. fp32 in/out.
//
//   p = fp8(x@Wl1); q = bf16(x@Wr1 + b1)      (k2: persistent MFMA proj, LDS weights)
//   h = bf16(relu(mean_nbr(p) + q))            (fused: gather 2 nodes/wave -> LDS tile)
//   u = fp8(h@Wl2); v = bf16(h@Wr2 + b2)       (fused: per-block 16-row MFMA proj2)
//   out = log_softmax(mean_nbr(u) + v)         (r12 gather: 1 node/wave, padded lists)
//
// r14: structural round. (1) proj2 fused into agg_relu: 512-thr block = 16-node tile;
// gather writes h to LDS[16][136]; 8 waves each do one (mat,ct) slice = 4 MFMA.
// Deletes proj2 dispatch + hb 51MB round-trip. u8/v now SEPARATE buffers (p8/q still
// being gathered while u8/v written). (2) k2 proj1 persistent: 316 blocks stage W
// once, tile-stride loop (no churn, staging amortized 2.5x). (3) agg_lsm back to r12
// 1-node/wave (r13 dual-node regressed agg_relu 44->48; ILP/TLP trade is neutral).

typedef __attribute__((ext_vector_type(8))) short short8;   // 8 x bf16 = 4 VGPRs
typedef __attribute__((ext_vector_type(4))) float f32x4;
typedef __attribute__((ext_vector_type(2))) float f32x2;

#define NPB 512          // nodes per bucket (dst >> 9)
#define BCAP 16384       // edge capacity per bucket (padded mean ~11.8K)
#define CHUNK 8192       // edges per bucket_scatter block

__device__ __forceinline__ ushort f2bf(float f) {           // round-to-nearest-even
    unsigned u = __float_as_uint(f);
    return (ushort)((u + 0x7fff + ((u >> 16) & 1)) >> 16);
}
__device__ __forceinline__ float bflo(unsigned v) { return __uint_as_float(v << 16); }
__device__ __forceinline__ float bfhi(unsigned v) { return __uint_as_float(v & 0xffff0000u); }
__device__ __forceinline__ unsigned pk4bf(float a, float b) {   // 1 VOP3 (RNE)
    unsigned r;
    asm("v_cvt_pk_bf16_f32 %0, %1, %2" : "=v"(r) : "v"(a), "v"(b));
    return r;
}
__device__ __forceinline__ f32x2 shflx2(f32x2 v, int m) {
    f32x2 r; r[0] = __shfl_xor(v[0], m); r[1] = __shfl_xor(v[1], m); return r;
}

// ---------- weight repack into MFMA fragment order ---------------------------------
// Wf idx = ((ct*16 + kc)*16 + m)*8 + j holds W[k=kc*8+j][c=ct*16+m]
__device__ __forceinline__ void wfrag_one(const float* W, ushort* Wf, int i, int COLS) {
    int j = i & 7, m = (i >> 3) & 15, kc = (i >> 7) & 15, ct = i >> 11;
    Wf[i] = f2bf(W[(kc * 8 + j) * COLS + ct * 16 + m]);
}

// ---------- K1: bucket_scatter (blocks 0..NSC) || cvt_w (rest) ---------------------
__global__ void __launch_bounds__(256)
k1_scatter_cvtw(const int* __restrict__ src, const int* __restrict__ dst,
                int* __restrict__ bcount, unsigned* __restrict__ bbuf, int E, int NSC,
                const float* __restrict__ Wl1, const float* __restrict__ Wr1,
                const float* __restrict__ Wl2, const float* __restrict__ Wr2,
                ushort* __restrict__ Wf_l1, ushort* __restrict__ Wf_r1,
                ushort* __restrict__ Wf_l2, ushort* __restrict__ Wf_r2) {
    int tid = threadIdx.x;
    if ((int)blockIdx.x >= NSC) {
        int i = ((int)blockIdx.x - NSC) * 256 + tid;   // 49152 total
        if (i < 16384)       wfrag_one(Wl1, Wf_l1, i, 128);
        else if (i < 32768)  wfrag_one(Wr1, Wf_r1, i - 16384, 128);
        else if (i < 40960)  wfrag_one(Wl2, Wf_l2, i - 32768, 64);
        else if (i < 49152)  wfrag_one(Wr2, Wf_r2, i - 40960, 64);
        return;
    }
    __shared__ unsigned entry[CHUNK];        // 32 KB: (src<<9)|(dst&511)
    __shared__ unsigned char ebkt[CHUNK];    // 8 KB: bucket id (dst>>9 < 256)
    __shared__ int lhist[256], lbase[256], lcur[256];
    lhist[tid] = 0;
    __syncthreads();
    int e0 = blockIdx.x * CHUNK;
    int cnt = min(CHUNK, E - e0);
    int nv = cnt >> 2;
    for (int t = tid; t < nv; t += 256) {
        int4 d4 = ((const int4*)(dst + e0))[t];
        int4 s4 = ((const int4*)(src + e0))[t];
        int i = t * 4;
        int b0 = d4.x >> 9, b1 = d4.y >> 9, b2 = d4.z >> 9, b3 = d4.w >> 9;
        entry[i + 0] = ((unsigned)s4.x << 9) | (unsigned)(d4.x & 511);
        entry[i + 1] = ((unsigned)s4.y << 9) | (unsigned)(d4.y & 511);
        entry[i + 2] = ((unsigned)s4.z << 9) | (unsigned)(d4.z & 511);
        entry[i + 3] = ((unsigned)s4.w << 9) | (unsigned)(d4.w & 511);
        ebkt[i + 0] = (unsigned char)b0; ebkt[i + 1] = (unsigned char)b1;
        ebkt[i + 2] = (unsigned char)b2; ebkt[i + 3] = (unsigned char)b3;
        atomicAdd(&lhist[b0], 1); atomicAdd(&lhist[b1], 1);
        atomicAdd(&lhist[b2], 1); atomicAdd(&lhist[b3], 1);
    }
    for (int i = (nv << 2) + tid; i < cnt; i += 256) {
        int d = dst[e0 + i], s = src[e0 + i];
        int b = d >> 9;
        entry[i] = ((unsigned)s << 9) | (unsigned)(d & 511);
        ebkt[i] = (unsigned char)b;
        atomicAdd(&lhist[b], 1);
    }
    __syncthreads();
    int h = lhist[tid];
    lbase[tid] = (h > 0) ? atomicAdd(&bcount[tid], h) : 0;
    lcur[tid] = 0;
    __syncthreads();
    for (int i = tid; i < cnt; i += 256) {
        int b = ebkt[i];
        int o = atomicAdd(&lcur[b], 1);
        bbuf[(long)b * BCAP + lbase[b] + o] = entry[i];
    }
}

// ---------- stage both weight fragment arrays into LDS (linear copy, 512 thr) ------
template <int CTOT>
__device__ __forceinline__ void stage_weights(const ushort* __restrict__ Wfl,
                                              const ushort* __restrict__ Wfr,
                                              ushort* dst, int tid) {
    constexpr int HALF = CTOT / 2;            // ushorts per matrix
    constexpr int ITERS = (CTOT * 2) / 8192;  // 512 thr * 16B per iter
#pragma unroll
    for (int r = 0; r < ITERS; ++r) {
        int u = r * 4096 + tid * 8;           // ushort index; half uniform per r
        const ushort* s = (u < HALF) ? (Wfl + u) : (Wfr + (u - HALF));
        *(short8*)(dst + u) = *(const short8*)s;
    }
}

// ---------- projection tile: p = fp8(X@Wl), q = bf16(X@Wr + b), W already in LDS ---
// Operand-swapped MFMA; 512 threads, 8 waves x 16 rows. Row N = zero sentinel.
template <int COLS, bool F32IN>
__device__ __forceinline__ void proj_tile(int bid, int tid,
                            const void* __restrict__ xin,
                            const ushort* Wl, const ushort* Wr,
                            const float* __restrict__ bias,
                            unsigned char* __restrict__ p8, ushort* __restrict__ q, int N) {
    constexpr int CT = COLS / 16;
    int wave = tid >> 6, lane = tid & 63;
    int quad = lane >> 4, m = lane & 15;
    long row0 = (long)bid * 128 + wave * 16;
    long node = row0 + m;
    long arow = (node < N) ? node : (N - 1);

    f32x4 accp[CT], accq[CT];
#pragma unroll
    for (int ct = 0; ct < CT; ++ct) { accp[ct] = (f32x4)0.0f; accq[ct] = (f32x4)0.0f; }

#pragma unroll
    for (int kk = 0; kk < 128; kk += 32) {
        short8 b;                            // B-frag: B[k][n=lane&15] = x[node][k]
        if (F32IN) {
            const float* xf = (const float*)xin + arow * 128 + kk + quad * 8;
            float4 f0 = *(const float4*)xf;
            float4 f1 = *(const float4*)(xf + 4);
            union { short8 s; unsigned u[4]; } bu;
            bu.u[0] = pk4bf(f0.x, f0.y);
            bu.u[1] = pk4bf(f0.z, f0.w);
            bu.u[2] = pk4bf(f1.x, f1.y);
            bu.u[3] = pk4bf(f1.z, f1.w);
            b = bu.s;
        } else {
            b = *(const short8*)((const ushort*)xin + arow * 128 + kk + quad * 8);
        }
        int kc = (kk >> 3) + quad;
#pragma unroll
        for (int ct = 0; ct < CT; ++ct) {
            int boff = ((ct * 16 + kc) * 16 + m) * 8;      // 32-bit LDS addressing
            short8 al = *(const short8*)(Wl + boff);       // ds_read_b128
            short8 ar = *(const short8*)(Wr + boff);
            accp[ct] = __builtin_amdgcn_mfma_f32_16x16x32_bf16(al, b, accp[ct], 0, 0, 0);
            accq[ct] = __builtin_amdgcn_mfma_f32_16x16x32_bf16(ar, b, accq[ct], 0, 0, 0);
        }
    }

    if (node <= N) {                          // row N = zero sentinel
        unsigned msk = (node == N) ? 0u : ~0u;
#pragma unroll
        for (int ct = 0; ct < CT; ++ct) {
            int c0 = ct * 16 + quad * 4;
            float4 bv = *(const float4*)(bias + c0);
            float q0 = accq[ct][0] + bv.x, q1 = accq[ct][1] + bv.y;
            float q2 = accq[ct][2] + bv.z, q3 = accq[ct][3] + bv.w;
            unsigned w = (unsigned)__builtin_amdgcn_cvt_pk_fp8_f32(accp[ct][0], accp[ct][1], 0, false);
            w = (unsigned)__builtin_amdgcn_cvt_pk_fp8_f32(accp[ct][2], accp[ct][3], (int)w, true);
            *(unsigned*)(p8 + node * COLS + c0) = w & msk;
            uint2 qw; qw.x = pk4bf(q0, q1) & msk; qw.y = pk4bf(q2, q3) & msk;
            *(uint2*)(q + node * COLS + c0) = qw;
        }
    }
}

// ---------- K2: build_csr (blocks 0..NB) || persistent proj1 -----------------------
// 512 threads, 64KB dynamic LDS. Proj blocks (NBcsr..NBcsr+PGRID) stage weights ONCE
// then tile-stride over NT tiles (no churn). CSR blocks: LDS entry cache + scan.
__global__ void __launch_bounds__(512, 4)
k2_csr_proj1(const unsigned* __restrict__ bbuf, const int* __restrict__ bcount,
             int* __restrict__ rsd,            // [2N]: {row_start, padded_deg}
             float* __restrict__ inv_deg, int* __restrict__ ssrc,
             int NBcsr, int PGRID, int NT, int N,
             const float* __restrict__ x,
             const ushort* __restrict__ Wfl, const ushort* __restrict__ Wfr,
             const float* __restrict__ bias,
             unsigned char* __restrict__ p8, ushort* __restrict__ q) {
    extern __shared__ char smem[];
    int tid = threadIdx.x;
    if ((int)blockIdx.x >= NBcsr) {
        ushort* wsm = (ushort*)smem;           // 64KB: Wfl then Wfr fragments
        stage_weights<2 * 128 * 128>(Wfl, Wfr, wsm, tid);
        __syncthreads();
        for (int t = (int)blockIdx.x - NBcsr; t < NT; t += PGRID)
            proj_tile<128, true>(t, tid, x, wsm, wsm + 128 * 128, bias, p8, q, N);
        return;
    }
    int* sdeg = (int*)smem;           // [512]
    int* lcur = sdeg + NPB;           // [512]
    int* wsum = lcur + NPB;           // [16] (padded to keep ecache 16B-aligned)
    unsigned* ecache = (unsigned*)(wsum + 16);   // 15344 entries (57KB)
    const int ECAPV = 3836;           // uint4 slots in ecache
    int b = blockIdx.x;
    int node0 = b * NPB;
    sdeg[tid] = 0;
    __syncthreads();
    int cnt = bcount[b];
    long base = (long)b * BCAP;
    const unsigned* bb = bbuf + base;
    int nv = cnt >> 2;
    int cnv = min(nv, ECAPV);
    for (int t = tid; t < nv; t += 512) {          // histogram + LDS entry cache
        uint4 e = ((const uint4*)bb)[t];
        if (t < cnv) ((uint4*)ecache)[t] = e;
        atomicAdd(&sdeg[e.x & 511], 1);
        atomicAdd(&sdeg[e.y & 511], 1);
        atomicAdd(&sdeg[e.z & 511], 1);
        atomicAdd(&sdeg[e.w & 511], 1);
    }
    for (int i = (nv << 2) + tid; i < cnt; i += 512)
        atomicAdd(&sdeg[bb[i] & 511], 1);
    __syncthreads();
    int lane = tid & 63, wv = tid >> 6;
    int c0 = sdeg[tid];
    int dp = (c0 + 15) & ~15;                       // padded degree
    int v = dp;                                     // wave-shuffle inclusive scan of dp
#pragma unroll
    for (int o = 1; o < 64; o <<= 1) {
        int t = __shfl_up(v, o);
        if (lane >= o) v += t;
    }
    if (lane == 63) wsum[wv] = v;
    __syncthreads();
    int add = 0;
    for (int w = 0; w < wv; ++w) add += wsum[w];
    int rs0 = v + add - dp;                         // bucket-local exclusive prefix
    lcur[tid] = rs0;
    if (node0 + tid < N) {
        int2 rv; rv.x = (int)(base + rs0); rv.y = dp;
        *(int2*)(rsd + 2 * (node0 + tid)) = rv;
        inv_deg[node0 + tid] = 1.0f / (float)(c0 > 1 ? c0 : 1);
    }
    __syncthreads();
    for (int t = tid; t < cnv; t += 512) {         // scatter from LDS cache
        uint4 e = ((const uint4*)ecache)[t];
        int p0 = atomicAdd(&lcur[e.x & 511], 1);
        int p1 = atomicAdd(&lcur[e.y & 511], 1);
        int p2 = atomicAdd(&lcur[e.z & 511], 1);
        int p3 = atomicAdd(&lcur[e.w & 511], 1);
        ssrc[base + p0] = (int)(e.x >> 9);
        ssrc[base + p1] = (int)(e.y >> 9);
        ssrc[base + p2] = (int)(e.z >> 9);
        ssrc[base + p3] = (int)(e.w >> 9);
    }
    for (int t = cnv + tid; t < nv; t += 512) {    // overflow (never in practice)
        uint4 e = ((const uint4*)bb)[t];
        int p0 = atomicAdd(&lcur[e.x & 511], 1);
        int p1 = atomicAdd(&lcur[e.y & 511], 1);
        int p2 = atomicAdd(&lcur[e.z & 511], 1);
        int p3 = atomicAdd(&lcur[e.w & 511], 1);
        ssrc[base + p0] = (int)(e.x >> 9);
        ssrc[base + p1] = (int)(e.y >> 9);
        ssrc[base + p2] = (int)(e.z >> 9);
        ssrc[base + p3] = (int)(e.w >> 9);
    }
    for (int i = (nv << 2) + tid; i < cnt; i += 512) {
        unsigned w = bb[i];
        int pos = atomicAdd(&lcur[w & 511], 1);
        ssrc[base + pos] = (int)(w >> 9);
    }
    // padding fill (disjoint from scatter ranges -> no barrier needed)
    for (int i = c0; i < dp; ++i) ssrc[base + rs0 + i] = N;
    if (tid == 511) {                               // bucket tail for prefetch overrun
        int tot = v + add;
        for (int k = 0; k < 16; ++k) ssrc[base + tot + k] = N;
    }
}

// ---------- fused: h = relu(mean_nbr(p)+q) -> LDS tile -> u8/v = proj2(h) ----------
// 512 thr = 8 waves x 2 nodes = 16-node tile. Gather phase = r13 dual-node (padded
// lists, no predication). h lands in hs[16][136] bf16. Then wave w computes output
// slice (mat = w&1, ct = w>>1): 4 MFMA over K=128. Weights staged at block start.
__global__ void __launch_bounds__(512, 6)
agg_relu_proj2(const unsigned char* __restrict__ p8,  // (N+1) x 128 fp8, row N = 0
               const ushort* __restrict__ q,          // (N+1) x 128 bf16
               const int* __restrict__ ssrc,
               const int* __restrict__ rsd,           // [2N] {row_start, padded_deg}
               const float* __restrict__ inv_deg,
               const ushort* __restrict__ Wfl, const ushort* __restrict__ Wfr,
               const float* __restrict__ bias,
               unsigned char* __restrict__ u8,        // (N+1) x 64 fp8 out
               ushort* __restrict__ v,                // N x 64 bf16 out
               int N) {
    __shared__ ushort wsm[2 * 64 * 128];   // 32 KB weight fragments
    __shared__ ushort hs[16][136];         // h tile; row stride 272B (16B-aligned)
    int tid = threadIdx.x;
    stage_weights<2 * 64 * 128>(Wfl, Wfr, wsm, tid);   // barrier deferred to pre-MFMA

    int wave = tid >> 6, lane = tid & 63;
    int row0 = (int)blockIdx.x * 16;
    int nA = row0 + wave * 2, nB = nA + 1;
    int cA = (nA < N) ? nA : N - 1;                // clamps are no-ops at N=100000
    int cB = (nB < N) ? nB : N - 1;
    int g = lane >> 4, lm = lane & 15;             // 4 edge slots / cols lm*8..lm*8+7
    int2 rvA = *(const int2*)(rsd + 2 * cA);
    int2 rvB = *(const int2*)(rsd + 2 * cB);
    int dpA = rvA.y, dpB = rvB.y;
    float ivA = inv_deg[cA], ivB = inv_deg[cB];
    uint4 qvA = make_uint4(0u,0u,0u,0u), qvB = make_uint4(0u,0u,0u,0u);
    if (g == 0) {
        qvA = *(const uint4*)(q + (long)cA * 128 + lm * 8);
        qvB = *(const uint4*)(q + (long)cB * 128 + lm * 8);
    }
    const int* spA = ssrc + rvA.x;
    const int* spB = ssrc + rvB.x;
    const unsigned char* pb = p8 + lm * 8;
    f32x2 aA0=(f32x2)0.f, aA1=(f32x2)0.f, aA2=(f32x2)0.f, aA3=(f32x2)0.f;
    f32x2 aB0=(f32x2)0.f, aB1=(f32x2)0.f, aB2=(f32x2)0.f, aB3=(f32x2)0.f;
    int4 sA = *(const int4*)(spA + 4 * g);
    int4 sB = *(const int4*)(spB + 4 * g);
    int dmin = min(dpA, dpB);
    int j = 0;
    for (; j < dmin; j += 16) {                    // dual-issue: 8 gathers in flight
        uint2 a0 = *(const uint2*)(pb + (unsigned)sA.x * 128u);
        uint2 a1 = *(const uint2*)(pb + (unsigned)sA.y * 128u);
        uint2 a2 = *(const uint2*)(pb + (unsigned)sA.z * 128u);
        uint2 a3 = *(const uint2*)(pb + (unsigned)sA.w * 128u);
        uint2 b0 = *(const uint2*)(pb + (unsigned)sB.x * 128u);
        uint2 b1 = *(const uint2*)(pb + (unsigned)sB.y * 128u);
        uint2 b2 = *(const uint2*)(pb + (unsigned)sB.z * 128u);
        uint2 b3 = *(const uint2*)(pb + (unsigned)sB.w * 128u);
        sA = *(const int4*)(spA + j + 16 + 4 * g);
        sB = *(const int4*)(spB + j + 16 + 4 * g);
        aA0 += __builtin_amdgcn_cvt_pk_f32_fp8((int)a0.x, false);
        aA1 += __builtin_amdgcn_cvt_pk_f32_fp8((int)a0.x, true);
        aA2 += __builtin_amdgcn_cvt_pk_f32_fp8((int)a0.y, false);
        aA3 += __builtin_amdgcn_cvt_pk_f32_fp8((int)a0.y, true);
        aA0 += __builtin_amdgcn_cvt_pk_f32_fp8((int)a1.x, false);
        aA1 += __builtin_amdgcn_cvt_pk_f32_fp8((int)a1.x, true);
        aA2 += __builtin_amdgcn_cvt_pk_f32_fp8((int)a1.y, false);
        aA3 += __builtin_amdgcn_cvt_pk_f32_fp8((int)a1.y, true);
        aA0 += __builtin_amdgcn_cvt_pk_f32_fp8((int)a2.x, false);
        aA1 += __builtin_amdgcn_cvt_pk_f32_fp8((int)a2.x, true);
        aA2 += __builtin_amdgcn_cvt_pk_f32_fp8((int)a2.y, false);
        aA3 += __builtin_amdgcn_cvt_pk_f32_fp8((int)a2.y, true);
        aA0 += __builtin_amdgcn_cvt_pk_f32_fp8((int)a3.x, false);
        aA1 += __builtin_amdgcn_cvt_pk_f32_fp8((int)a3.x, true);
        aA2 += __builtin_amdgcn_cvt_pk_f32_fp8((int)a3.y, false);
        aA3 += __builtin_amdgcn_cvt_pk_f32_fp8((int)a3.y, true);
        aB0 += __builtin_amdgcn_cvt_pk_f32_fp8((int)b0.x, false);
        aB1 += __builtin_amdgcn_cvt_pk_f32_fp8((int)b0.x, true);
        aB2 += __builtin_amdgcn_cvt_pk_f32_fp8((int)b0.y, false);
        aB3 += __builtin_amdgcn_cvt_pk_f32_fp8((int)b0.y, true);
        aB0 += __builtin_amdgcn_cvt_pk_f32_fp8((int)b1.x, false);
        aB1 += __builtin_amdgcn_cvt_pk_f32_fp8((int)b1.x, true);
        aB2 += __builtin_amdgcn_cvt_pk_f32_fp8((int)b1.y, false);
        aB3 += __builtin_amdgcn_cvt_pk_f32_fp8((int)b1.y, true);
        aB0 += __builtin_amdgcn_cvt_pk_f32_fp8((int)b2.x, false);
        aB1 += __builtin_amdgcn_cvt_pk_f32_fp8((int)b2.x, true);
        aB2 += __builtin_amdgcn_cvt_pk_f32_fp8((int)b2.y, false);
        aB3 += __builtin_amdgcn_cvt_pk_f32_fp8((int)b2.y, true);
        aB0 += __builtin_amdgcn_cvt_pk_f32_fp8((int)b3.x, false);
        aB1 += __builtin_amdgcn_cvt_pk_f32_fp8((int)b3.x, true);
        aB2 += __builtin_amdgcn_cvt_pk_f32_fp8((int)b3.y, false);
        aB3 += __builtin_amdgcn_cvt_pk_f32_fp8((int)b3.y, true);
    }
    for (; j < dpA; j += 16) {                     // A continuation (rare)
        uint2 a0 = *(const uint2*)(pb + (unsigned)sA.x * 128u);
        uint2 a1 = *(const uint2*)(pb + (unsigned)sA.y * 128u);
        uint2 a2 = *(const uint2*)(pb + (unsigned)sA.z * 128u);
        uint2 a3 = *(const uint2*)(pb + (unsigned)sA.w * 128u);
        sA = *(const int4*)(spA + j + 16 + 4 * g);
        aA0 += __builtin_amdgcn_cvt_pk_f32_fp8((int)a0.x, false);
        aA1 += __builtin_amdgcn_cvt_pk_f32_fp8((int)a0.x, true);
        aA2 += __builtin_amdgcn_cvt_pk_f32_fp8((int)a0.y, false);
        aA3 += __builtin_amdgcn_cvt_pk_f32_fp8((int)a0.y, true);
        aA0 += __builtin_amdgcn_cvt_pk_f32_fp8((int)a1.x, false);
        aA1 += __builtin_amdgcn_cvt_pk_f32_fp8((int)a1.x, true);
        aA2 += __builtin_amdgcn_cvt_pk_f32_fp8((int)a1.y, false);
        aA3 += __builtin_amdgcn_cvt_pk_f32_fp8((int)a1.y, true);
        aA0 += __builtin_amdgcn_cvt_pk_f32_fp8((int)a2.x, false);
        aA1 += __builtin_amdgcn_cvt_pk_f32_fp8((int)a2.x, true);
        aA2 += __builtin_amdgcn_cvt_pk_f32_fp8((int)a2.y, false);
        aA3 += __builtin_amdgcn_cvt_pk_f32_fp8((int)a2.y, true);
        aA0 += __builtin_amdgcn_cvt_pk_f32_fp8((int)a3.x, false);
        aA1 += __builtin_amdgcn_cvt_pk_f32_fp8((int)a3.x, true);
        aA2 += __builtin_amdgcn_cvt_pk_f32_fp8((int)a3.y, false);
        aA3 += __builtin_amdgcn_cvt_pk_f32_fp8((int)a3.y, true);
    }
    for (; j < dpB; j += 16) {                     // B continuation (rare)
        uint2 b0 = *(const uint2*)(pb + (unsigned)sB.x * 128u);
        uint2 b1 = *(const uint2*)(pb + (unsigned)sB.y * 128u);
        uint2 b2 = *(const uint2*)(pb + (unsigned)sB.z * 128u);
        uint2 b3 = *(const uint2*)(pb + (unsigned)sB.w * 128u);
        sB = *(const int4*)(spB + j + 16 + 4 * g);
        aB0 += __builtin_amdgcn_cvt_pk_f32_fp8((int)b0.x, false);
        aB1 += __builtin_amdgcn_cvt_pk_f32_fp8((int)b0.x, true);
        aB2 += __builtin_amdgcn_cvt_pk_f32_fp8((int)b0.y, false);
        aB3 += __builtin_amdgcn_cvt_pk_f32_fp8((int)b0.y, true);
        aB0 += __builtin_amdgcn_cvt_pk_f32_fp8((int)b1.x, false);
        aB1 += __builtin_amdgcn_cvt_pk_f32_fp8((int)b1.x, true);
        aB2 += __builtin_amdgcn_cvt_pk_f32_fp8((int)b1.y, false);
        aB3 += __builtin_amdgcn_cvt_pk_f32_fp8((int)b1.y, true);
        aB0 += __builtin_amdgcn_cvt_pk_f32_fp8((int)b2.x, false);
        aB1 += __builtin_amdgcn_cvt_pk_f32_fp8((int)b2.x, true);
        aB2 += __builtin_amdgcn_cvt_pk_f32_fp8((int)b2.y, false);
        aB3 += __builtin_amdgcn_cvt_pk_f32_fp8((int)b2.y, true);
        aB0 += __builtin_amdgcn_cvt_pk_f32_fp8((int)b3.x, false);
        aB1 += __builtin_amdgcn_cvt_pk_f32_fp8((int)b3.x, true);
        aB2 += __builtin_amdgcn_cvt_pk_f32_fp8((int)b3.y, false);
        aB3 += __builtin_amdgcn_cvt_pk_f32_fp8((int)b3.y, true);
    }
    aA0 += shflx2(aA0, 16); aA1 += shflx2(aA1, 16);
    aA2 += shflx2(aA2, 16); aA3 += shflx2(aA3, 16);
    aB0 += shflx2(aB0, 16); aB1 += shflx2(aB1, 16);
    aB2 += shflx2(aB2, 16); aB3 += shflx2(aB3, 16);
    aA0 += shflx2(aA0, 32); aA1 += shflx2(aA1, 32);
    aA2 += shflx2(aA2, 32); aA3 += shflx2(aA3, 32);
    aB0 += shflx2(aB0, 32); aB1 += shflx2(aB1, 32);
    aB2 += shflx2(aB2, 32); aB3 += shflx2(aB3, 32);
    if (g == 0) {                                  // h rows -> LDS tile (bf16)
        float h0 = fmaxf(aA0[0] * ivA + bflo(qvA.x), 0.f);
        float h1 = fmaxf(aA0[1] * ivA + bfhi(qvA.x), 0.f);
        float h2 = fmaxf(aA1[0] * ivA + bflo(qvA.y), 0.f);
        float h3 = fmaxf(aA1[1] * ivA + bfhi(qvA.y), 0.f);
        float h4 = fmaxf(aA2[0] * ivA + bflo(qvA.z), 0.f);
        float h5 = fmaxf(aA2[1] * ivA + bfhi(qvA.z), 0.f);
        float h6 = fmaxf(aA3[0] * ivA + bflo(qvA.w), 0.f);
        float h7 = fmaxf(aA3[1] * ivA + bfhi(qvA.w), 0.f);
        uint4 hwA;
        hwA.x = pk4bf(h0, h1); hwA.y = pk4bf(h2, h3);
        hwA.z = pk4bf(h4, h5); hwA.w = pk4bf(h6, h7);
        *(uint4*)(&hs[wave * 2 + 0][lm * 8]) = hwA;
        float g0 = fmaxf(aB0[0] * ivB + bflo(qvB.x), 0.f);
        float g1 = fmaxf(aB0[1] * ivB + bfhi(qvB.x), 0.f);
        float g2 = fmaxf(aB1[0] * ivB + bflo(qvB.y), 0.f);
        float g3 = fmaxf(aB1[1] * ivB + bfhi(qvB.y), 0.f);
        float g4 = fmaxf(aB2[0] * ivB + bflo(qvB.z), 0.f);
        float g5 = fmaxf(aB2[1] * ivB + bfhi(qvB.z), 0.f);
        float g6 = fmaxf(aB3[0] * ivB + bflo(qvB.w), 0.f);
        float g7 = fmaxf(aB3[1] * ivB + bfhi(qvB.w), 0.f);
        uint4 hwB;
        hwB.x = pk4bf(g0, g1); hwB.y = pk4bf(g2, g3);
        hwB.z = pk4bf(g4, g5); hwB.w = pk4bf(g6, g7);
        *(uint4*)(&hs[wave * 2 + 1][lm * 8]) = hwB;
    }
    __syncthreads();
    // proj2: wave w -> (mat = w&1, ct = w>>1); lane (quad=g, m=lm) -> node row0+m
    {
        int mat = wave & 1, ct = wave >> 1;
        const ushort* W = mat ? (wsm + 64 * 128) : wsm;
        f32x4 acc = (f32x4)0.0f;
#pragma unroll
        for (int kk = 0; kk < 128; kk += 32) {
            short8 bfr = *(const short8*)(&hs[lm][kk + g * 8]);
            int kc = (kk >> 3) + g;
            short8 afr = *(const short8*)(W + ((ct * 16 + kc) * 16 + lm) * 8);
            acc = __builtin_amdgcn_mfma_f32_16x16x32_bf16(afr, bfr, acc, 0, 0, 0);
        }
        int node = row0 + lm;
        if (node < N) {
            int c0 = ct * 16 + g * 4;
            if (mat == 0) {                        // u8 = fp8(h @ Wl2)
                unsigned w = (unsigned)__builtin_amdgcn_cvt_pk_fp8_f32(acc[0], acc[1], 0, false);
                w = (unsigned)__builtin_amdgcn_cvt_pk_fp8_f32(acc[2], acc[3], (int)w, true);
                *(unsigned*)(u8 + (long)node * 64 + c0) = w;
            } else {                               // v = bf16(h @ Wr2 + b2)
                float4 bv = *(const float4*)(bias + c0);
                uint2 qw;
                qw.x = pk4bf(acc[0] + bv.x, acc[1] + bv.y);
                qw.y = pk4bf(acc[2] + bv.z, acc[3] + bv.w);
                *(uint2*)(v + (long)node * 64 + c0) = qw;
            }
        }
    }
    if (blockIdx.x == 0 && tid < 16)               // u8 sentinel row N = 0
        ((unsigned*)(u8 + (long)N * 64))[tid] = 0u;
}

// ---------- layer-2 aggregate + log_softmax (r12: 1 node/wave, padded) -------------
__global__ void __launch_bounds__(256)
agg_lsm_kernel(const unsigned char* __restrict__ u8,   // (N+1) x 64 fp8, row N = 0
               const ushort* __restrict__ v,           // N x 64 bf16
               const int* __restrict__ ssrc,
               const int* __restrict__ rsd,            // [2N] {row_start, padded_deg}
               const float* __restrict__ inv_deg,
               float* __restrict__ out, int N) {
    int wave = threadIdx.x >> 6, lane = threadIdx.x & 63;
    int n = blockIdx.x * 4 + wave;
    if (n >= N) return;
    int g = lane >> 4, lm = lane & 15;             // 4 edge slots / cols lm*4..lm*4+3
    int2 rv = *(const int2*)(rsd + 2 * n);
    int start = rv.x, dp = rv.y;
    float iv = inv_deg[n];                         // hoisted
    uint2 vv2 = *(const uint2*)(v + (long)n * 64 + lm * 4);   // hoisted
    const int* sp = ssrc + start;
    const unsigned char* ub = u8 + lm * 4;
    f32x2 a0 = (f32x2)0.f, a1 = (f32x2)0.f;
    int4 s = *(const int4*)(sp + 4 * g);           // slot g: edges 4g..4g+3
    for (int j = 0; j < dp; j += 16) {
        unsigned v0 = *(const unsigned*)(ub + (unsigned)s.x * 64u);
        unsigned v1 = *(const unsigned*)(ub + (unsigned)s.y * 64u);
        unsigned v2 = *(const unsigned*)(ub + (unsigned)s.z * 64u);
        unsigned v3 = *(const unsigned*)(ub + (unsigned)s.w * 64u);
        s = *(const int4*)(sp + j + 16 + 4 * g);   // prefetch next batch (tail-safe)
        a0 += __builtin_amdgcn_cvt_pk_f32_fp8((int)v0, false);
        a1 += __builtin_amdgcn_cvt_pk_f32_fp8((int)v0, true);
        a0 += __builtin_amdgcn_cvt_pk_f32_fp8((int)v1, false);
        a1 += __builtin_amdgcn_cvt_pk_f32_fp8((int)v1, true);
        a0 += __builtin_amdgcn_cvt_pk_f32_fp8((int)v2, false);
        a1 += __builtin_amdgcn_cvt_pk_f32_fp8((int)v2, true);
        a0 += __builtin_amdgcn_cvt_pk_f32_fp8((int)v3, false);
        a1 += __builtin_amdgcn_cvt_pk_f32_fp8((int)v3, true);
    }
    a0 += shflx2(a0, 16); a1 += shflx2(a1, 16);    // merge 4 slots
    a0 += shflx2(a0, 32); a1 += shflx2(a1, 32);

    float z0 = a0[0] * iv + bflo(vv2.x), z1 = a0[1] * iv + bfhi(vv2.x);
    float z2 = a1[0] * iv + bflo(vv2.y), z3 = a1[1] * iv + bfhi(vv2.y);
    float mx = fmaxf(fmaxf(z0, z1), fmaxf(z2, z3));
#pragma unroll
    for (int o = 8; o > 0; o >>= 1) mx = fmaxf(mx, __shfl_xor(mx, o));   // over lm bits
    float e = (__expf(z0 - mx) + __expf(z1 - mx)) + (__expf(z2 - mx) + __expf(z3 - mx));
#pragma unroll
    for (int o = 8; o > 0; o >>= 1) e += __shfl_xor(e, o);
    float ls = mx + __logf(e);
    if (g == 0) {                                  // 16 lanes store 4 floats each
        float4 o0;
        o0.x = z0 - ls; o0.y = z1 - ls; o0.z = z2 - ls; o0.w = z3 - ls;
        *(float4*)(out + (long)n * 64 + lm * 4) = o0;
    }
}

// -----------------------------------------------------------------------------------
extern "C" void kernel_launch(void* const* d_in, const int* in_sizes, int n_in,
                              void* d_out, int out_size, void* d_ws, size_t ws_size,
                              hipStream_t stream) {
    const float* x   = (const float*)d_in[0];
    const int*   ei  = (const int*)d_in[1];
    const float* Wl1 = (const float*)d_in[2];
    const float* Wr1 = (const float*)d_in[3];
    const float* b1  = (const float*)d_in[4];
    const float* Wl2 = (const float*)d_in[5];
    const float* Wr2 = (const float*)d_in[6];
    const float* b2  = (const float*)d_in[7];

    const int N = in_sizes[0] / 128;
    const int E = in_sizes[1] / 2;
    const int* src = ei;
    const int* dst = ei + E;
    const int NB = (N + NPB - 1) / NPB;             // 196 buckets for N=100000
    const int NSC = (E + CHUNK - 1) / CHUNK;        // 196 scatter blocks

    size_t off = 0;
    auto take = [&](size_t nbytes) -> void* {
        void* ptr = (void*)((char*)d_ws + off);
        off += (nbytes + 255) & ~(size_t)255;
        return ptr;
    };
    int*      bcount    = (int*)take((size_t)NB * 4);
    unsigned* bbuf      = (unsigned*)take((size_t)NB * BCAP * 4);   // 12.8 MB
    int*      rsd       = (int*)take((size_t)N * 8);                // {row_start, pdeg}
    float*    inv_deg   = (float*)take((size_t)N * 4);
    int*      ssrc      = (int*)take((size_t)NB * BCAP * 4);        // 12.8 MB (bucket-strided)
    unsigned char* p8   = (unsigned char*)take((size_t)(N + 1) * 128);    // +sentinel row
    ushort*   q         = (ushort*)take((size_t)(N + 1) * 128 * 2);       // +sentinel row
    unsigned char* u8   = (unsigned char*)take((size_t)(N + 1) * 64);     // SEPARATE (aliasing!)
    ushort*   v         = (ushort*)take((size_t)N * 64 * 2);
    ushort*   Wf_l1     = (ushort*)take(128 * 128 * 2);
    ushort*   Wf_r1     = (ushort*)take(128 * 128 * 2);
    ushort*   Wf_l2     = (ushort*)take(64 * 128 * 2);
    ushort*   Wf_r2     = (ushort*)take(64 * 128 * 2);
    (void)ws_size; (void)n_in; (void)out_size;

    static bool attr_set = false;                   // allow 64KB dynamic LDS for k2
    if (!attr_set) {
        hipFuncSetAttribute((const void*)k2_csr_proj1,
                            hipFuncAttributeMaxDynamicSharedMemorySize, 65536);
        attr_set = true;
    }

    hipMemsetAsync(bcount, 0, (size_t)NB * 4, stream);

    // K1: scatter || weight repack (independent)
    k1_scatter_cvtw<<<NSC + 192, 256, 0, stream>>>(src, dst, bcount, bbuf, E, NSC,
                                                   Wl1, Wr1, Wl2, Wr2,
                                                   Wf_l1, Wf_r1, Wf_l2, Wf_r2);

    // K2: build_csr || persistent proj1 (196 + 316 = 512 blocks = 2/CU everywhere)
    const int PGRID = 316;
    const int NT = (N + 127) / 128;                 // 782 proj tiles
    k2_csr_proj1<<<NB + PGRID, 512, 65536, stream>>>(bbuf, bcount, rsd, inv_deg, ssrc,
                                                     NB, PGRID, NT, N, x,
                                                     Wf_l1, Wf_r1, b1, p8, q);

    // fused layer-1 aggregate + proj2 (16 nodes/block)
    agg_relu_proj2<<<(N + 15) / 16, 512, 0, stream>>>(p8, q, ssrc, rsd, inv_deg,
                                                      Wf_l2, Wf_r2, b2, u8, v, N);

    // layer-2 aggregate + log_softmax
    agg_lsm_kernel<<<(N + 3) / 4, 256, 0, stream>>>(u8, v, ssrc, rsd, inv_deg,
                                                    (float*)d_out, N);
}